// Round 11
// baseline (692.229 us; speedup 1.0000x reference)
//
#include <hip/hip_runtime.h>
#include <hip/hip_fp16.h>
#include <math.h>

typedef _Float16 f16;
typedef _Float16 half8 __attribute__((ext_vector_type(8)));
typedef _Float16 half4 __attribute__((ext_vector_type(4)));
typedef float float4v __attribute__((ext_vector_type(4)));
typedef unsigned int uint4v __attribute__((ext_vector_type(4)));

#define AS1 __attribute__((address_space(1)))
#define AS3 __attribute__((address_space(3)))

// ---------------- workspace layout ----------------
constexpr size_t alup(size_t x){ return (x + 255) & ~(size_t)255; }
constexpr size_t OFF_MT   = 0;                                    // 150*150 fp32 (zeroed)
constexpr size_t OFF_DEG  = alup(OFF_MT + 150*150*4);             // 150 fp32 (zeroed)
constexpr size_t OFF_HT0  = alup(OFF_DEG + 150*4);                // 32*512 u32 {tag|f16} (zeroed)
constexpr size_t OFF_HT1  = alup(OFF_HT0 + (size_t)32*512*4);     // 32*512 u32 (zeroed)
constexpr size_t OFF_WFCP = alup(OFF_HT1 + (size_t)32*512*4);     // 256*192 f16 padded (zeroed)
constexpr size_t OFF_WH2P = alup(OFF_WFCP + (size_t)256*192*2);   // 512*160 f16 padded (zeroed)
constexpr size_t OFF_DECB = alup(OFF_WH2P + (size_t)512*160*2);   // 3200*192 f16 (zeroed)
constexpr size_t ZONE_END = alup(OFF_DECB + (size_t)3200*192*2);
constexpr size_t OFF_EDST = ZONE_END;                             // 1500 int
constexpr size_t OFF_EVAL = alup(OFF_EDST + 1500*4);              // 1500 fp32
constexpr size_t OFF_PT   = alup(OFF_EVAL + 1500*4);              // 513*452 fp32 Wi2 prefix (cols o)
constexpr size_t OFF_XF   = alup(OFF_PT + (size_t)513*452*4);     // 480000 fp32 (x in row layout)
constexpr size_t OFF_SS   = alup(OFF_XF + (size_t)480000*4);      // 480000 fp32 (agg scalar)
constexpr size_t OFF_XT   = alup(OFF_SS + (size_t)480000*4);      // 3200*4800 f16
constexpr size_t OFF_WI1H = alup(OFF_XT + (size_t)3200*4800*2);   // 1536*4800 f16
constexpr size_t OFF_XI1  = alup(OFF_WI1H + (size_t)1536*4800*2); // 3200*1536 f16

// fast gates: __expf lowers to v_exp_f32 fast path (~2ulp; absmax slack ~5x)
static __device__ __forceinline__ float fsig(float x){ return 1.0f/(1.0f + __expf(-x)); }
static __device__ __forceinline__ float ftanh(float x){
    x = fminf(fmaxf(x, -15.f), 15.f);
    float e = __expf(2.0f*x);
    return (e - 1.0f)/(e + 1.0f);
}

// ---------------- topk with inline normalize ----------------
__global__ void k_topk(const float* __restrict__ emb, int* __restrict__ EDST,
                       float* __restrict__ EVAL, float* __restrict__ DEG) {
    __shared__ float WnT[32*152];
    __shared__ float invn[160];
    __shared__ float As[160];
    int tid = threadIdx.x;
    int i = blockIdx.x;  // row
    for (int idx = tid; idx < 4800; idx += 256) {
        int jj = idx >> 5, c = idx & 31;
        WnT[c*152 + jj] = emb[idx];
    }
    __syncthreads();
    if (tid < 150) {
        float s = 0.f;
        #pragma unroll
        for (int c = 0; c < 32; ++c) { float v = WnT[c*152 + tid]; s += v*v; }
        invn[tid] = 1.0f / fmaxf(sqrtf(s), 1e-8f);
    }
    __syncthreads();
    for (int idx = tid; idx < 4800; idx += 256) {
        int jj = idx >> 5, c = idx & 31;
        WnT[c*152 + jj] *= invn[jj];
    }
    __syncthreads();
    int j = tid;
    if (j < 150) {
        float a = 0.f;
        #pragma unroll
        for (int c = 0; c < 32; ++c) a += WnT[c*152 + i] * WnT[c*152 + j];
        a = (j == i) ? 0.f : fmaxf(a, 0.f);
        As[j] = a;
    }
    __syncthreads();
    if (j < 150) {
        float aj = As[j];
        int cnt = 0;
        for (int m = 0; m < 150; ++m) {
            float am = As[m];
            cnt += (am > aj) || (am == aj && m < j);
        }
        if (cnt < 10) {
            EDST[i*10 + cnt] = j;
            EVAL[i*10 + cnt] = aj;
            atomicAdd(&DEG[j], aj);
        }
    }
}

// ---------------- merged prep: finalize + weight cvts + perm + Wi2 wave-scan ----------------
// 0: MT | [1,28801): Wi1 | [28801,28889): W_fc (ld 192) | [28889,29153): Wh2 (ld 160)
// [29153,31028): window permute | [31028,31141): Wi2 prefix via wave-scan (1 wave/row)
// R10 bug: prefix was 2 blocks x 512 SERIAL iterations w/ stride-2KB loads (~50+us tail
// on an otherwise instant kernel). Now: lane l holds 8 contiguous row values (coalesced),
// __shfl_up inclusive scan of lane sums, 8 writes/lane.
__global__ void k_prep(const int* __restrict__ EDST, const float* __restrict__ EVAL,
                       const float* __restrict__ DEG, float* __restrict__ MT,
                       const float* __restrict__ Wi1, f16* __restrict__ WI1H,
                       const float* __restrict__ W_fc, f16* __restrict__ WFCP,
                       const float* __restrict__ Wh2, f16* __restrict__ WH2P,
                       const float* __restrict__ window, float* __restrict__ XF,
                       const float* __restrict__ Wi2, float* __restrict__ PT) {
    int b = blockIdx.x, tid = threadIdx.x;
    if (b == 0) {
        __shared__ float dinv[160];
        if (tid < 150) {
            float d = DEG[tid];
            dinv[tid] = (d > 0.f) ? rsqrtf(d) : 0.f;
        }
        __syncthreads();
        for (int e = tid; e < 1500; e += 256) {
            int src = e / 10;
            int dst = EDST[e];
            MT[src*150 + dst] = dinv[src] * EVAL[e] * dinv[dst];
        }
    } else if (b < 28801) {
        int idx = (b - 1)*256 + tid;              // 1536*4800 = 7372800, exact
        WI1H[idx] = (f16)Wi1[idx];
    } else if (b < 28889) {
        int idx = (b - 28801)*256 + tid;          // 150*150 = 22500
        if (idx < 22500) {
            int r = idx / 150, c = idx % 150;
            WFCP[r*192 + c] = (f16)W_fc[idx];
        }
    } else if (b < 29153) {
        int idx = (b - 28889)*256 + tid;          // 450*150 = 67500
        if (idx < 67500) {
            int r = idx / 150, c = idx % 150;
            WH2P[r*160 + c] = (f16)Wh2[idx];
        }
    } else if (b < 31028) {
        int idx = (b - 29153)*256 + tid;          // 480000, exact
        float v = window[idx];
        int bb = idx / 15000;
        int r = idx % 15000;
        int t = r / 150, n = r % 150;
        XF[bb*15000 + n*100 + t] = v;
    } else {
        // Wi2 prefix: one wave per row o; PT[k][o] layout (coalesced reads in gru2)
        int row = (b - 31028)*4 + (tid >> 6);
        int lane = tid & 63;
        if (row < 450) {
            const float* src = Wi2 + (size_t)row*512 + lane*8;
            float v[8]; float s = 0.f;
            #pragma unroll
            for (int i = 0; i < 8; ++i) { v[i] = src[i]; s += v[i]; }
            float inc = s;
            #pragma unroll
            for (int d = 1; d < 64; d <<= 1) {
                float up = __shfl_up(inc, d, 64);
                if (lane >= d) inc += up;
            }
            float run = inc - s;   // exclusive prefix of this lane's chunk
            if (lane == 0) PT[row] = 0.f;
            #pragma unroll
            for (int i = 0; i < 8; ++i) {
                run += v[i];
                PT[(size_t)(lane*8 + i + 1)*452 + row] = run;
            }
        }
    }
}

// ---------------- scrambled ARMA aggregation: per contiguous 150-chunk of XF ----------------
__global__ void k_conv(const float* __restrict__ XF, const float* __restrict__ MT,
                       float* __restrict__ SS) {
    __shared__ float xs[152];
    int tid = threadIdx.x;
    int base = blockIdx.x * 150;
    if (tid < 150) xs[tid] = XF[base + tid];
    __syncthreads();
    if (tid < 150) {
        float s = 0.f;
        for (int m = 0; m < 150; ++m) s += MT[m*150 + tid] * xs[m];
        SS[base + tid] = s;
    }
}

// ---------------- epilogue: gelu(SS*wi + XF*wr + b) + emb -> xt (f16) ----------------
__global__ void k_xt(const float* __restrict__ SS, const float* __restrict__ XF,
                     const float* __restrict__ w_init, const float* __restrict__ w_root,
                     const float* __restrict__ arma_b, const float* __restrict__ emb,
                     f16* __restrict__ xt) {
    __shared__ float ssl[152];
    __shared__ float xfl[152];
    int tid = threadIdx.x;
    int bid = blockIdx.x;           // = b*100 + t
    int b = bid / 100, t = bid % 100;
    if (tid < 150) {
        int f = b*15000 + tid*100 + t;
        ssl[tid] = SS[f];
        xfl[tid] = XF[f];
    }
    __syncthreads();
    for (int e = tid; e < 4800; e += 256) {
        int n = e >> 5, c = e & 31;
        float pre = ssl[n]*w_init[c] + xfl[n]*w_root[c] + arma_b[c];
        float g = 0.5f * pre * (1.0f + erff(pre * 0.70710678118654752f));
        xt[(size_t)bid*4800 + e] = (f16)(g + emb[e]);
    }
}

// ---------------- f16 MFMA GEMM, 64x128 tile, BK=64, N-major block order ----------------
template <typename TC>
__global__ void k_gemm(const f16* __restrict__ A, const f16* __restrict__ Bm,
                       const float* __restrict__ bias, TC* __restrict__ C,
                       int K, int ldc, int nvalid, int ntm) {
    __shared__ f16 As[64*64];
    __shared__ f16 Bs[128*64];
    int tid = threadIdx.x;
    int lane = tid & 63, wave = tid >> 6;
    int wm = wave >> 1, wn = wave & 1;           // wave tile 32 x 64
    int tm = blockIdx.x % ntm, tn = blockIdx.x / ntm;
    int m0 = tm * 64, n0 = tn * 128;
    int lrow = lane & 15, quad = lane >> 4;

    float4v acc[2][4];
    #pragma unroll
    for (int mi = 0; mi < 2; ++mi)
        #pragma unroll
        for (int ni = 0; ni < 4; ++ni)
            acc[mi][ni] = (float4v){0.f, 0.f, 0.f, 0.f};

    for (int k0 = 0; k0 < K; k0 += 64) {
        #pragma unroll
        for (int i = 0; i < 2; ++i) {            // A: 512 chunks of 8 halves
            int cid = i*256 + tid;
            int row = cid >> 3, cq = cid & 7;
            int cbase = cid & ~63;               // wave-uniform
            const f16* ga = A + (size_t)(m0+row)*K + k0 + cq*8;
            __builtin_amdgcn_global_load_lds((const AS1 void*)ga, (AS3 void*)(As + cbase*8), 16, 0, 0);
        }
        #pragma unroll
        for (int i = 0; i < 4; ++i) {            // B: 1024 chunks
            int cid = i*256 + tid;
            int row = cid >> 3, cq = cid & 7;
            int cbase = cid & ~63;
            const f16* gb = Bm + (size_t)(n0+row)*K + k0 + cq*8;
            __builtin_amdgcn_global_load_lds((const AS1 void*)gb, (AS3 void*)(Bs + cbase*8), 16, 0, 0);
        }
        __syncthreads();
        #pragma unroll
        for (int kk = 0; kk < 2; ++kk) {
            half8 aF[2], bF[4];
            #pragma unroll
            for (int mi = 0; mi < 2; ++mi)
                aF[mi] = *(const half8*)&As[(wm*32 + mi*16 + lrow)*64 + kk*32 + quad*8];
            #pragma unroll
            for (int ni = 0; ni < 4; ++ni)
                bF[ni] = *(const half8*)&Bs[(wn*64 + ni*16 + lrow)*64 + kk*32 + quad*8];
            #pragma unroll
            for (int mi = 0; mi < 2; ++mi)
                #pragma unroll
                for (int ni = 0; ni < 4; ++ni)
                    acc[mi][ni] = __builtin_amdgcn_mfma_f32_16x16x32_f16(aF[mi], bF[ni], acc[mi][ni], 0, 0, 0);
        }
        __syncthreads();
    }

    #pragma unroll
    for (int ni = 0; ni < 4; ++ni) {
        int gcol = n0 + wn*64 + ni*16 + lrow;
        if (gcol >= nvalid) continue;
        float bv = bias[gcol];
        #pragma unroll
        for (int mi = 0; mi < 2; ++mi) {
            int growb = m0 + wm*32 + mi*16 + quad*4;
            #pragma unroll
            for (int r = 0; r < 4; ++r)
                C[(size_t)(growb + r)*ldc + gcol] = (TC)(acc[mi][ni][r] + bv);
        }
    }
}

// ---------------- GRU1: 16 groups x 16 blocks; AGPR B-frags + u32 tag|f16 exchange ----
__global__ __launch_bounds__(256, 1)
void k_gru1(const f16* __restrict__ xi1, const float* __restrict__ Wh1,
            const float* __restrict__ bh1, unsigned* __restrict__ ht0,
            unsigned* __restrict__ ht1) {
    __shared__ __align__(16) f16 hA[16*640];    // 20KB: [k0][row*40+kk], rows 0,1 real
    __shared__ float ghs[192];
    int tid = threadIdx.x;
    int g = blockIdx.x & 15;
    int j = blockIdx.x >> 4;
    int b0 = g * 2;
    int lane = tid & 63, wave = tid >> 6;
    int lrow = lane & 15, quad = lane >> 4;

    // B-fragments (waves 0..2): tiles 2w, 2w+1; B[n][k]: n=lrow, k=k0*32+quad*8+i
    half8 Bf0[16], Bf1[16];
    if (wave < 3) {
        #pragma unroll
        for (int tile = 0; tile < 2; ++tile) {
            int rr = (wave*2 + tile)*16 + lrow;
            int grow = (rr >> 5)*512 + (j << 5) + (rr & 31);
            const float* wp = Wh1 + (size_t)grow*512 + quad*8;
            #pragma unroll
            for (int k0 = 0; k0 < 16; ++k0) {
                float4v w0 = *(const float4v*)(wp + k0*32);
                float4v w1 = *(const float4v*)(wp + k0*32 + 4);
                half8 hb;
                hb[0]=(f16)w0[0]; hb[1]=(f16)w0[1]; hb[2]=(f16)w0[2]; hb[3]=(f16)w0[3];
                hb[4]=(f16)w1[0]; hb[5]=(f16)w1[1]; hb[6]=(f16)w1[2]; hb[7]=(f16)w1[3];
                if (tile == 0) Bf0[k0] = hb; else Bf1[k0] = hb;
            }
        }
    }

    // gates state (tid<64): own hidden + biases + xi in registers
    float hold = 0.f, bhr = 0.f, bhz = 0.f, bhn = 0.f;
    f16 xir = (f16)0.f, xiz = (f16)0.f, xin = (f16)0.f;
    size_t xb = 0;
    if (tid < 64) {
        int bl = tid >> 5, i = tid & 31;
        int col = (j << 5) + i;
        bhr = bh1[col]; bhz = bh1[512 + col]; bhn = bh1[1024 + col];
        xb = (size_t)((b0 + bl)*100)*1536 + col;
        xir = xi1[xb]; xiz = xi1[xb + 512]; xin = xi1[xb + 1024];   // t=0
    }
    // staging: thread -> 4 consecutive u32 h-slots (16B)
    int sbl = tid >> 7;
    int kb  = (tid & 127) << 2;

    for (int t = 0; t < 100; ++t) {
        const unsigned* cur = (t & 1) ? ht1 : ht0;
        unsigned* nxt = (t & 1) ? ht0 : ht1;
        // ---- stage h: poll tag-in-data, place f16 A-fragment ----
        {
            const unsigned* p = cur + (size_t)(b0 + sbl)*512 + kb;
            uint4v A4;
            unsigned tagw = (unsigned)t << 16;
            for (;;) {
                asm volatile("global_load_dwordx4 %0, %1, off sc0 sc1\n\ts_waitcnt vmcnt(0)"
                             : "=v"(A4) : "v"(p) : "memory");
                if ((A4[0] & 0xffff0000u) == tagw && (A4[1] & 0xffff0000u) == tagw &&
                    (A4[2] & 0xffff0000u) == tagw && (A4[3] & 0xffff0000u) == tagw) break;
                __builtin_amdgcn_s_sleep(1);
            }
            union { unsigned short s[4]; half4 h; } cv;
            cv.s[0] = (unsigned short)A4[0]; cv.s[1] = (unsigned short)A4[1];
            cv.s[2] = (unsigned short)A4[2]; cv.s[3] = (unsigned short)A4[3];
            *(half4*)&hA[(kb >> 5)*640 + sbl*40 + (kb & 31)] = cv.h;
        }
        __syncthreads();   // A

        if (wave < 3) {
            // split accumulator chains (2x8 deps instead of 1x16)
            float4v a0a = (float4v){0.f,0.f,0.f,0.f}, a0b = a0a, a1a = a0a, a1b = a0a;
            const f16* aB = &hA[lrow*40 + quad*8];
            #pragma unroll
            for (int k0 = 0; k0 < 16; k0 += 2) {
                half8 a0 = *(const half8*)(aB + k0*640);
                half8 a1 = *(const half8*)(aB + (k0+1)*640);
                a0a = __builtin_amdgcn_mfma_f32_16x16x32_f16(a0, Bf0[k0], a0a, 0, 0, 0);
                a1a = __builtin_amdgcn_mfma_f32_16x16x32_f16(a0, Bf1[k0], a1a, 0, 0, 0);
                a0b = __builtin_amdgcn_mfma_f32_16x16x32_f16(a1, Bf0[k0+1], a0b, 0, 0, 0);
                a1b = __builtin_amdgcn_mfma_f32_16x16x32_f16(a1, Bf1[k0+1], a1b, 0, 0, 0);
            }
            if (lane < 16) {   // C: col=lane, row=reg; rows 0,1 = batches
                int n0 = wave*2, n1 = n0 + 1;
                ghs[n0*16 + lane]      = a0a[0] + a0b[0];
                ghs[96 + n0*16 + lane] = a0a[1] + a0b[1];
                ghs[n1*16 + lane]      = a1a[0] + a1b[0];
                ghs[96 + n1*16 + lane] = a1a[1] + a1b[1];
            }
        }
        __syncthreads();   // B

        if (tid < 64) {
            int bl = tid >> 5, i = tid & 31;
            float xr_ = (float)xir, xz_ = (float)xiz, xn_ = (float)xin;
            // prefetch xi for t+1 (immutable; lands during next step's exchange)
            int tn = (t < 99) ? t + 1 : 99;
            size_t xo = xb + (size_t)tn*1536;
            xir = xi1[xo]; xiz = xi1[xo + 512]; xin = xi1[xo + 1024];
            float gr = ghs[bl*96 + i]      + bhr;
            float gz = ghs[bl*96 + 32 + i] + bhz;
            float gn = ghs[bl*96 + 64 + i] + bhn;
            float r = fsig(xr_ + gr);
            float z = fsig(xz_ + gz);
            float n = ftanh(xn_ + r*gn);
            float hnew = (1.f - z)*n + z*hold;
            hold = hnew;
            union { f16 h; unsigned short s; } hb; hb.h = (f16)hnew;
            unsigned pk = ((unsigned)(t + 1) << 16) | (unsigned)hb.s;
            __hip_atomic_store(nxt + (size_t)(b0 + bl)*512 + (j << 5) + i, pk,
                               __ATOMIC_RELAXED, __HIP_MEMORY_SCOPE_AGENT);
        }
    }
}

// ---------------- GRU2: MFMA + on-the-fly xi2 (fused repeat-interleave prefix trick) ----
// h_end is STATIC across the scan -> each block loads its batch's 512 h values once
// (LDS fp32), then computes xis[t+1] during the MFMA phase via PT segment differences
// (<=7 segs, coalesced L2-hot loads), double-buffered. Replaces the k_xi2 kernel and
// the XI2H global round trip.
__global__ __launch_bounds__(256, 1)
void k_gru2(const unsigned* __restrict__ ht0, const float* __restrict__ PT,
            const float* __restrict__ bi2, const f16* __restrict__ wh2p,
            const float* __restrict__ bh2, f16* __restrict__ decb) {
    __shared__ __align__(16) f16 hA[5*640];     // [k0][row*40+kk], row 0 real
    __shared__ float ghs[512];
    __shared__ float hs[512];                   // static h_end (fp32)
    __shared__ float xis[2][456];
    int tid = threadIdx.x;
    int b = blockIdx.x;
    int lane = tid & 63, wave = tid >> 6;
    int lrow = lane & 15, quad = lane >> 4;

    // load static h_end (tagged {tag|f16}, low 16 bits = value)
    {
        union { unsigned short s; f16 h; } c1, c2;
        c1.s = (unsigned short)ht0[(b << 9) + tid];
        c2.s = (unsigned short)ht0[(b << 9) + tid + 256];
        hs[tid] = (float)c1.h;
        hs[tid + 256] = (float)c2.h;
    }
    for (int i = tid; i < 5*640; i += 256) hA[i] = (f16)0.f;
    __syncthreads();

    // B-fragments: 8 tiles x 5 k-chunks per wave
    half8 Bf[8][5];
    #pragma unroll
    for (int tt = 0; tt < 8; ++tt) {
        int rn = (wave*8 + tt)*16 + lrow;
        const f16* wp = wh2p + (size_t)rn*160 + quad*8;
        #pragma unroll
        for (int k0 = 0; k0 < 5; ++k0)
            Bf[tt][k0] = *(const half8*)(wp + k0*32);
    }

    float hold = 0.f, bhr = 0.f, bhz = 0.f, bhn = 0.f;
    float b2a = bi2[tid < 450 ? tid : 0];
    float b2b = (tid + 256 < 450) ? bi2[tid + 256] : 0.f;
    if (tid < 150) {
        bhr = bh2[tid]; bhz = bh2[150 + tid]; bhn = bh2[300 + tid];
    }
    // xis[0] for t=0
    {
        int m0 = 0;   // base = 0
        #pragma unroll
        for (int q = 0; q < 2; ++q) {
            int o = tid + q*256;
            if (o < 450) {
                float acc = q ? b2b : b2a;
                #pragma unroll
                for (int s = 0; s < 7; ++s) {
                    int klo = (m0 + s)*100;     klo = klo < 0 ? 0 : klo;
                    int khi = (m0 + s + 1)*100; khi = khi > 512 ? 512 : khi;
                    if (klo < khi)
                        acc += hs[m0 + s] * (PT[(size_t)khi*452 + o] - PT[(size_t)klo*452 + o]);
                }
                xis[0][o] = acc;
            }
        }
    }
    __syncthreads();

    for (int t = 0; t < 100; ++t) {
        // MFMA: gh = Wh2 @ h  (A row 0 = h)
        float4v acc[8];
        #pragma unroll
        for (int tt = 0; tt < 8; ++tt) acc[tt] = (float4v){0.f,0.f,0.f,0.f};
        #pragma unroll
        for (int k0 = 0; k0 < 5; ++k0) {
            half8 a = *(const half8*)&hA[k0*640 + lrow*40 + quad*8];
            #pragma unroll
            for (int tt = 0; tt < 8; ++tt)
                acc[tt] = __builtin_amdgcn_mfma_f32_16x16x32_f16(a, Bf[tt][k0], acc[tt], 0, 0, 0);
        }
        if (lane < 16) {
            #pragma unroll
            for (int tt = 0; tt < 8; ++tt)
                ghs[(wave*8 + tt)*16 + lane] = acc[tt][0];
        }
        // compute xis for t+1 (overlaps MFMA pipe; reads static hs + L2-hot PT)
        if (t < 99) {
            int base = (t + 1) * 512;
            int m0 = base / 100;
            #pragma unroll
            for (int q = 0; q < 2; ++q) {
                int o = tid + q*256;
                if (o < 450) {
                    float acc2 = q ? b2b : b2a;
                    #pragma unroll
                    for (int s = 0; s < 7; ++s) {
                        int klo = (m0 + s)*100 - base;     klo = klo < 0 ? 0 : klo;
                        int khi = (m0 + s + 1)*100 - base; khi = khi > 512 ? 512 : khi;
                        if (klo < khi)
                            acc2 += hs[m0 + s] * (PT[(size_t)khi*452 + o] - PT[(size_t)klo*452 + o]);
                    }
                    xis[(t + 1) & 1][o] = acc2;
                }
            }
        }
        __syncthreads();       // ghs + xis_next ready; hA reads done

        if (tid < 150) {
            const float* xc = xis[t & 1];
            float r = fsig(xc[tid] + ghs[tid] + bhr);
            float z = fsig(xc[150 + tid] + ghs[150 + tid] + bhz);
            float n = ftanh(xc[300 + tid] + r*(ghs[300 + tid] + bhn));
            float hnew = (1.f - z)*n + z*hold;
            hold = hnew;
            f16 hh = (f16)hnew;
            hA[(tid >> 5)*640 + (tid & 31)] = hh;
            decb[((size_t)b*100 + t)*192 + tid] = hh;
        }
        __syncthreads();       // hA(t+1) ready, xis[t&1] free
    }
}

// ---------------- launch ----------------
extern "C" void kernel_launch(void* const* d_in, const int* in_sizes, int n_in,
                              void* d_out, int out_size, void* d_ws, size_t ws_size,
                              hipStream_t stream) {
    const float* window = (const float*)d_in[0];
    const float* emb    = (const float*)d_in[1];
    const float* w_init = (const float*)d_in[2];
    const float* w_root = (const float*)d_in[3];
    const float* arma_b = (const float*)d_in[4];
    const float* Wi1    = (const float*)d_in[5];
    const float* Wh1    = (const float*)d_in[6];
    const float* bi1    = (const float*)d_in[7];
    const float* bh1    = (const float*)d_in[8];
    const float* Wi2    = (const float*)d_in[9];
    const float* Wh2    = (const float*)d_in[10];
    const float* bi2    = (const float*)d_in[11];
    const float* bh2    = (const float*)d_in[12];
    const float* W_fc   = (const float*)d_in[13];
    const float* b_fc   = (const float*)d_in[14];
    float* out = (float*)d_out;

    char* ws = (char*)d_ws;
    float*    MT   = (float*)(ws + OFF_MT);
    float*    DEG  = (float*)(ws + OFF_DEG);
    unsigned* HT0  = (unsigned*)(ws + OFF_HT0);
    unsigned* HT1  = (unsigned*)(ws + OFF_HT1);
    f16*      WFCP = (f16*)  (ws + OFF_WFCP);
    f16*      WH2P = (f16*)  (ws + OFF_WH2P);
    f16*      DECB = (f16*)  (ws + OFF_DECB);
    int*      EDST = (int*)  (ws + OFF_EDST);
    float*    EVAL = (float*)(ws + OFF_EVAL);
    float*    PT   = (float*)(ws + OFF_PT);
    float*    XF   = (float*)(ws + OFF_XF);
    float*    SS   = (float*)(ws + OFF_SS);
    f16*      XT   = (f16*)  (ws + OFF_XT);
    f16*      WI1H = (f16*)  (ws + OFF_WI1H);
    f16*      XI1H = (f16*)  (ws + OFF_XI1);

    // zero the zone (MT scatter target, deg, tagged h buffers, padded weights, dec)
    hipMemsetAsync(d_ws, 0, ZONE_END, stream);

    // graph build (norm inlined in topk)
    k_topk<<<150, 256, 0, stream>>>(emb, EDST, EVAL, DEG);

    // merged prep: finalize + weight cvts + window permute + Wi2 wave-scan prefix
    k_prep<<<31141, 256, 0, stream>>>(EDST, EVAL, DEG, MT,
                                      Wi1, WI1H, W_fc, WFCP, Wh2, WH2P,
                                      window, XF, Wi2, PT);

    // scrambled aggregation, epilogue -> xt (f16)
    k_conv<<<3200, 256, 0, stream>>>(XF, MT, SS);
    k_xt<<<3200, 256, 0, stream>>>(SS, XF, w_init, w_root, arma_b, emb, XT);

    // xi1 = xt @ Wi1^T + bi1   [3200 x 1536] f16 out, 64x128 tiles, N-major, ntm=50
    k_gemm<f16><<<50*12, 256, 0, stream>>>(XT, WI1H, bi1, XI1H, 4800, 1536, 1536, 50);

    // GRU1 scan -> h_end (tagged f16) in HT0
    k_gru1<<<256, 256, 0, stream>>>(XI1H, Wh1, bh1, HT0, HT1);

    // GRU2 scan (with fused xi2) -> dec (f16, padded K=192)
    k_gru2<<<32, 256, 0, stream>>>(HT0, PT, bi2, WH2P, bh2, DECB);

    // out = dec @ W_fc^T + b_fc  -> directly into d_out [3200 x 150] (fp32)
    k_gemm<float><<<50*2, 256, 0, stream>>>(DECB, WFCP, b_fc, out, 192, 150, 150, 50);

    (void)in_sizes; (void)n_in; (void)out_size; (void)ws_size;
}

// Round 12
// 519.283 us; speedup vs baseline: 1.3330x; 1.3330x over previous
//
#include <hip/hip_runtime.h>
#include <hip/hip_fp16.h>
#include <math.h>

typedef _Float16 f16;
typedef _Float16 half8 __attribute__((ext_vector_type(8)));
typedef _Float16 half4 __attribute__((ext_vector_type(4)));
typedef float float4v __attribute__((ext_vector_type(4)));
typedef unsigned int uint4v __attribute__((ext_vector_type(4)));

#define AS1 __attribute__((address_space(1)))
#define AS3 __attribute__((address_space(3)))

// ---------------- workspace layout ----------------
constexpr size_t alup(size_t x){ return (x + 255) & ~(size_t)255; }
constexpr size_t OFF_MT   = 0;                                    // 150*150 fp32 (zeroed)
constexpr size_t OFF_DEG  = alup(OFF_MT + 150*150*4);             // 150 fp32 (zeroed)
constexpr size_t OFF_HT0  = alup(OFF_DEG + 150*4);                // 32*512 u32 {tag|f16} (zeroed)
constexpr size_t OFF_HT1  = alup(OFF_HT0 + (size_t)32*512*4);     // 32*512 u32 (zeroed)
constexpr size_t OFF_WFCP = alup(OFF_HT1 + (size_t)32*512*4);     // 256*192 f16 padded (zeroed)
constexpr size_t OFF_WH2P = alup(OFF_WFCP + (size_t)256*192*2);   // 512*160 f16 padded (zeroed)
constexpr size_t OFF_DECB = alup(OFF_WH2P + (size_t)512*160*2);   // 3200*192 f16 (zeroed)
constexpr size_t ZONE_END = alup(OFF_DECB + (size_t)3200*192*2);
constexpr size_t OFF_EDST = ZONE_END;                             // 1500 int
constexpr size_t OFF_EVAL = alup(OFF_EDST + 1500*4);              // 1500 fp32
constexpr size_t OFF_PT   = alup(OFF_EVAL + 1500*4);              // 513*452 fp32 Wi2 prefix (cols o)
constexpr size_t OFF_XF   = alup(OFF_PT + (size_t)513*452*4);     // 480000 fp32 (x in row layout)
constexpr size_t OFF_SS   = alup(OFF_XF + (size_t)480000*4);      // 480000 fp32 (agg scalar)
constexpr size_t OFF_XT   = alup(OFF_SS + (size_t)480000*4);      // 3200*4800 f16
constexpr size_t OFF_WI1H = alup(OFF_XT + (size_t)3200*4800*2);   // 1536*4800 f16
constexpr size_t OFF_XI1  = alup(OFF_WI1H + (size_t)1536*4800*2); // 3200*1536 f16
constexpr size_t OFF_XI2  = alup(OFF_XI1 + (size_t)3200*1536*2);  // 3200*512 f16

// fast gates: __expf lowers to v_exp_f32 fast path (~2ulp; absmax slack ~5x)
static __device__ __forceinline__ float fsig(float x){ return 1.0f/(1.0f + __expf(-x)); }
static __device__ __forceinline__ float ftanh(float x){
    x = fminf(fmaxf(x, -15.f), 15.f);
    float e = __expf(2.0f*x);
    return (e - 1.0f)/(e + 1.0f);
}

// ---------------- topk with inline normalize ----------------
__global__ void k_topk(const float* __restrict__ emb, int* __restrict__ EDST,
                       float* __restrict__ EVAL, float* __restrict__ DEG) {
    __shared__ float WnT[32*152];
    __shared__ float invn[160];
    __shared__ float As[160];
    int tid = threadIdx.x;
    int i = blockIdx.x;  // row
    for (int idx = tid; idx < 4800; idx += 256) {
        int jj = idx >> 5, c = idx & 31;
        WnT[c*152 + jj] = emb[idx];
    }
    __syncthreads();
    if (tid < 150) {
        float s = 0.f;
        #pragma unroll
        for (int c = 0; c < 32; ++c) { float v = WnT[c*152 + tid]; s += v*v; }
        invn[tid] = 1.0f / fmaxf(sqrtf(s), 1e-8f);
    }
    __syncthreads();
    for (int idx = tid; idx < 4800; idx += 256) {
        int jj = idx >> 5, c = idx & 31;
        WnT[c*152 + jj] *= invn[jj];
    }
    __syncthreads();
    int j = tid;
    if (j < 150) {
        float a = 0.f;
        #pragma unroll
        for (int c = 0; c < 32; ++c) a += WnT[c*152 + i] * WnT[c*152 + j];
        a = (j == i) ? 0.f : fmaxf(a, 0.f);
        As[j] = a;
    }
    __syncthreads();
    if (j < 150) {
        float aj = As[j];
        int cnt = 0;
        for (int m = 0; m < 150; ++m) {
            float am = As[m];
            cnt += (am > aj) || (am == aj && m < j);
        }
        if (cnt < 10) {
            EDST[i*10 + cnt] = j;
            EVAL[i*10 + cnt] = aj;
            atomicAdd(&DEG[j], aj);
        }
    }
}

// ---------------- merged prep: finalize + weight cvts + perm + Wi2 wave-scan ----------------
__global__ void k_prep(const int* __restrict__ EDST, const float* __restrict__ EVAL,
                       const float* __restrict__ DEG, float* __restrict__ MT,
                       const float* __restrict__ Wi1, f16* __restrict__ WI1H,
                       const float* __restrict__ W_fc, f16* __restrict__ WFCP,
                       const float* __restrict__ Wh2, f16* __restrict__ WH2P,
                       const float* __restrict__ window, float* __restrict__ XF,
                       const float* __restrict__ Wi2, float* __restrict__ PT) {
    int b = blockIdx.x, tid = threadIdx.x;
    if (b == 0) {
        __shared__ float dinv[160];
        if (tid < 150) {
            float d = DEG[tid];
            dinv[tid] = (d > 0.f) ? rsqrtf(d) : 0.f;
        }
        __syncthreads();
        for (int e = tid; e < 1500; e += 256) {
            int src = e / 10;
            int dst = EDST[e];
            MT[src*150 + dst] = dinv[src] * EVAL[e] * dinv[dst];
        }
    } else if (b < 28801) {
        int idx = (b - 1)*256 + tid;              // 1536*4800 = 7372800, exact
        WI1H[idx] = (f16)Wi1[idx];
    } else if (b < 28889) {
        int idx = (b - 28801)*256 + tid;          // 150*150 = 22500
        if (idx < 22500) {
            int r = idx / 150, c = idx % 150;
            WFCP[r*192 + c] = (f16)W_fc[idx];
        }
    } else if (b < 29153) {
        int idx = (b - 28889)*256 + tid;          // 450*150 = 67500
        if (idx < 67500) {
            int r = idx / 150, c = idx % 150;
            WH2P[r*160 + c] = (f16)Wh2[idx];
        }
    } else if (b < 31028) {
        int idx = (b - 29153)*256 + tid;          // 480000, exact
        float v = window[idx];
        int bb = idx / 15000;
        int r = idx % 15000;
        int t = r / 150, n = r % 150;
        XF[bb*15000 + n*100 + t] = v;
    } else {
        // Wi2 prefix: one wave per row o; PT[k][o] layout (coalesced reads in k_xi2)
        int row = (b - 31028)*4 + (tid >> 6);
        int lane = tid & 63;
        if (row < 450) {
            const float* src = Wi2 + (size_t)row*512 + lane*8;
            float v[8]; float s = 0.f;
            #pragma unroll
            for (int i = 0; i < 8; ++i) { v[i] = src[i]; s += v[i]; }
            float inc = s;
            #pragma unroll
            for (int d = 1; d < 64; d <<= 1) {
                float up = __shfl_up(inc, d, 64);
                if (lane >= d) inc += up;
            }
            float run = inc - s;   // exclusive prefix of this lane's chunk
            if (lane == 0) PT[row] = 0.f;
            #pragma unroll
            for (int i = 0; i < 8; ++i) {
                run += v[i];
                PT[(size_t)(lane*8 + i + 1)*452 + row] = run;
            }
        }
    }
}

// ---------------- scrambled ARMA aggregation: per contiguous 150-chunk of XF ----------------
__global__ void k_conv(const float* __restrict__ XF, const float* __restrict__ MT,
                       float* __restrict__ SS) {
    __shared__ float xs[152];
    int tid = threadIdx.x;
    int base = blockIdx.x * 150;
    if (tid < 150) xs[tid] = XF[base + tid];
    __syncthreads();
    if (tid < 150) {
        float s = 0.f;
        for (int m = 0; m < 150; ++m) s += MT[m*150 + tid] * xs[m];
        SS[base + tid] = s;
    }
}

// ---------------- epilogue: gelu(SS*wi + XF*wr + b) + emb -> xt (f16) ----------------
__global__ void k_xt(const float* __restrict__ SS, const float* __restrict__ XF,
                     const float* __restrict__ w_init, const float* __restrict__ w_root,
                     const float* __restrict__ arma_b, const float* __restrict__ emb,
                     f16* __restrict__ xt) {
    __shared__ float ssl[152];
    __shared__ float xfl[152];
    int tid = threadIdx.x;
    int bid = blockIdx.x;           // = b*100 + t
    int b = bid / 100, t = bid % 100;
    if (tid < 150) {
        int f = b*15000 + tid*100 + t;
        ssl[tid] = SS[f];
        xfl[tid] = XF[f];
    }
    __syncthreads();
    for (int e = tid; e < 4800; e += 256) {
        int n = e >> 5, c = e & 31;
        float pre = ssl[n]*w_init[c] + xfl[n]*w_root[c] + arma_b[c];
        float g = 0.5f * pre * (1.0f + erff(pre * 0.70710678118654752f));
        xt[(size_t)bid*4800 + e] = (f16)(g + emb[e]);
    }
}

// ---------------- f16 MFMA GEMM, 64x128 tile, BK=64, N-major block order ----------------
template <typename TC>
__global__ void k_gemm(const f16* __restrict__ A, const f16* __restrict__ Bm,
                       const float* __restrict__ bias, TC* __restrict__ C,
                       int K, int ldc, int nvalid, int ntm) {
    __shared__ f16 As[64*64];
    __shared__ f16 Bs[128*64];
    int tid = threadIdx.x;
    int lane = tid & 63, wave = tid >> 6;
    int wm = wave >> 1, wn = wave & 1;           // wave tile 32 x 64
    int tm = blockIdx.x % ntm, tn = blockIdx.x / ntm;
    int m0 = tm * 64, n0 = tn * 128;
    int lrow = lane & 15, quad = lane >> 4;

    float4v acc[2][4];
    #pragma unroll
    for (int mi = 0; mi < 2; ++mi)
        #pragma unroll
        for (int ni = 0; ni < 4; ++ni)
            acc[mi][ni] = (float4v){0.f, 0.f, 0.f, 0.f};

    for (int k0 = 0; k0 < K; k0 += 64) {
        #pragma unroll
        for (int i = 0; i < 2; ++i) {            // A: 512 chunks of 8 halves
            int cid = i*256 + tid;
            int row = cid >> 3, cq = cid & 7;
            int cbase = cid & ~63;               // wave-uniform
            const f16* ga = A + (size_t)(m0+row)*K + k0 + cq*8;
            __builtin_amdgcn_global_load_lds((const AS1 void*)ga, (AS3 void*)(As + cbase*8), 16, 0, 0);
        }
        #pragma unroll
        for (int i = 0; i < 4; ++i) {            // B: 1024 chunks
            int cid = i*256 + tid;
            int row = cid >> 3, cq = cid & 7;
            int cbase = cid & ~63;
            const f16* gb = Bm + (size_t)(n0+row)*K + k0 + cq*8;
            __builtin_amdgcn_global_load_lds((const AS1 void*)gb, (AS3 void*)(Bs + cbase*8), 16, 0, 0);
        }
        __syncthreads();
        #pragma unroll
        for (int kk = 0; kk < 2; ++kk) {
            half8 aF[2], bF[4];
            #pragma unroll
            for (int mi = 0; mi < 2; ++mi)
                aF[mi] = *(const half8*)&As[(wm*32 + mi*16 + lrow)*64 + kk*32 + quad*8];
            #pragma unroll
            for (int ni = 0; ni < 4; ++ni)
                bF[ni] = *(const half8*)&Bs[(wn*64 + ni*16 + lrow)*64 + kk*32 + quad*8];
            #pragma unroll
            for (int mi = 0; mi < 2; ++mi)
                #pragma unroll
                for (int ni = 0; ni < 4; ++ni)
                    acc[mi][ni] = __builtin_amdgcn_mfma_f32_16x16x32_f16(aF[mi], bF[ni], acc[mi][ni], 0, 0, 0);
        }
        __syncthreads();
    }

    #pragma unroll
    for (int ni = 0; ni < 4; ++ni) {
        int gcol = n0 + wn*64 + ni*16 + lrow;
        if (gcol >= nvalid) continue;
        float bv = bias[gcol];
        #pragma unroll
        for (int mi = 0; mi < 2; ++mi) {
            int growb = m0 + wm*32 + mi*16 + quad*4;
            #pragma unroll
            for (int r = 0; r < 4; ++r)
                C[(size_t)(growb + r)*ldc + gcol] = (TC)(acc[mi][ni][r] + bv);
        }
    }
}

// ---------------- GRU1: 16 groups x 16 blocks; AGPR B-frags + u32 tag|f16 exchange ----
__global__ __launch_bounds__(256, 1)
void k_gru1(const f16* __restrict__ xi1, const float* __restrict__ Wh1,
            const float* __restrict__ bh1, unsigned* __restrict__ ht0,
            unsigned* __restrict__ ht1) {
    __shared__ __align__(16) f16 hA[16*640];    // 20KB: [k0][row*40+kk], rows 0,1 real
    __shared__ float ghs[192];
    int tid = threadIdx.x;
    int g = blockIdx.x & 15;
    int j = blockIdx.x >> 4;
    int b0 = g * 2;
    int lane = tid & 63, wave = tid >> 6;
    int lrow = lane & 15, quad = lane >> 4;

    // B-fragments (waves 0..2): tiles 2w, 2w+1; B[n][k]: n=lrow, k=k0*32+quad*8+i
    half8 Bf0[16], Bf1[16];
    if (wave < 3) {
        #pragma unroll
        for (int tile = 0; tile < 2; ++tile) {
            int rr = (wave*2 + tile)*16 + lrow;
            int grow = (rr >> 5)*512 + (j << 5) + (rr & 31);
            const float* wp = Wh1 + (size_t)grow*512 + quad*8;
            #pragma unroll
            for (int k0 = 0; k0 < 16; ++k0) {
                float4v w0 = *(const float4v*)(wp + k0*32);
                float4v w1 = *(const float4v*)(wp + k0*32 + 4);
                half8 hb;
                hb[0]=(f16)w0[0]; hb[1]=(f16)w0[1]; hb[2]=(f16)w0[2]; hb[3]=(f16)w0[3];
                hb[4]=(f16)w1[0]; hb[5]=(f16)w1[1]; hb[6]=(f16)w1[2]; hb[7]=(f16)w1[3];
                if (tile == 0) Bf0[k0] = hb; else Bf1[k0] = hb;
            }
        }
    }

    // gates state (tid<64): own hidden + biases + xi in registers
    float hold = 0.f, bhr = 0.f, bhz = 0.f, bhn = 0.f;
    f16 xir = (f16)0.f, xiz = (f16)0.f, xin = (f16)0.f;
    size_t xb = 0;
    if (tid < 64) {
        int bl = tid >> 5, i = tid & 31;
        int col = (j << 5) + i;
        bhr = bh1[col]; bhz = bh1[512 + col]; bhn = bh1[1024 + col];
        xb = (size_t)((b0 + bl)*100)*1536 + col;
        xir = xi1[xb]; xiz = xi1[xb + 512]; xin = xi1[xb + 1024];   // t=0
    }
    // staging: thread -> 4 consecutive u32 h-slots (16B)
    int sbl = tid >> 7;
    int kb  = (tid & 127) << 2;

    for (int t = 0; t < 100; ++t) {
        const unsigned* cur = (t & 1) ? ht1 : ht0;
        unsigned* nxt = (t & 1) ? ht0 : ht1;
        // ---- stage h: poll tag-in-data, place f16 A-fragment ----
        {
            const unsigned* p = cur + (size_t)(b0 + sbl)*512 + kb;
            uint4v A4;
            unsigned tagw = (unsigned)t << 16;
            for (;;) {
                asm volatile("global_load_dwordx4 %0, %1, off sc0 sc1\n\ts_waitcnt vmcnt(0)"
                             : "=v"(A4) : "v"(p) : "memory");
                if ((A4[0] & 0xffff0000u) == tagw && (A4[1] & 0xffff0000u) == tagw &&
                    (A4[2] & 0xffff0000u) == tagw && (A4[3] & 0xffff0000u) == tagw) break;
                __builtin_amdgcn_s_sleep(1);
            }
            union { unsigned short s[4]; half4 h; } cv;
            cv.s[0] = (unsigned short)A4[0]; cv.s[1] = (unsigned short)A4[1];
            cv.s[2] = (unsigned short)A4[2]; cv.s[3] = (unsigned short)A4[3];
            *(half4*)&hA[(kb >> 5)*640 + sbl*40 + (kb & 31)] = cv.h;
        }
        __syncthreads();   // A

        if (wave < 3) {
            // split accumulator chains (2x8 deps instead of 1x16)
            float4v a0a = (float4v){0.f,0.f,0.f,0.f}, a0b = a0a, a1a = a0a, a1b = a0a;
            const f16* aB = &hA[lrow*40 + quad*8];
            #pragma unroll
            for (int k0 = 0; k0 < 16; k0 += 2) {
                half8 a0 = *(const half8*)(aB + k0*640);
                half8 a1 = *(const half8*)(aB + (k0+1)*640);
                a0a = __builtin_amdgcn_mfma_f32_16x16x32_f16(a0, Bf0[k0], a0a, 0, 0, 0);
                a1a = __builtin_amdgcn_mfma_f32_16x16x32_f16(a0, Bf1[k0], a1a, 0, 0, 0);
                a0b = __builtin_amdgcn_mfma_f32_16x16x32_f16(a1, Bf0[k0+1], a0b, 0, 0, 0);
                a1b = __builtin_amdgcn_mfma_f32_16x16x32_f16(a1, Bf1[k0+1], a1b, 0, 0, 0);
            }
            if (lane < 16) {   // C: col=lane, row=reg; rows 0,1 = batches
                int n0 = wave*2, n1 = n0 + 1;
                ghs[n0*16 + lane]      = a0a[0] + a0b[0];
                ghs[96 + n0*16 + lane] = a0a[1] + a0b[1];
                ghs[n1*16 + lane]      = a1a[0] + a1b[0];
                ghs[96 + n1*16 + lane] = a1a[1] + a1b[1];
            }
        }
        __syncthreads();   // B

        if (tid < 64) {
            int bl = tid >> 5, i = tid & 31;
            float xr_ = (float)xir, xz_ = (float)xiz, xn_ = (float)xin;
            // prefetch xi for t+1 (immutable; lands during next step's exchange)
            int tn = (t < 99) ? t + 1 : 99;
            size_t xo = xb + (size_t)tn*1536;
            xir = xi1[xo]; xiz = xi1[xo + 512]; xin = xi1[xo + 1024];
            float gr = ghs[bl*96 + i]      + bhr;
            float gz = ghs[bl*96 + 32 + i] + bhz;
            float gn = ghs[bl*96 + 64 + i] + bhn;
            float r = fsig(xr_ + gr);
            float z = fsig(xz_ + gz);
            float n = ftanh(xn_ + r*gn);
            float hnew = (1.f - z)*n + z*hold;
            hold = hnew;
            union { f16 h; unsigned short s; } hb; hb.h = (f16)hnew;
            unsigned pk = ((unsigned)(t + 1) << 16) | (unsigned)hb.s;
            __hip_atomic_store(nxt + (size_t)(b0 + bl)*512 + (j << 5) + i, pk,
                               __ATOMIC_RELAXED, __HIP_MEMORY_SCOPE_AGENT);
        }
    }
}

// ---------------- xi2 via repeat-interleave structure (standalone, 3200 blocks) ----------
// R11 lesson: fusing this into gru2 (32 blocks, sequential loop) put ~14 L2-latency PT
// loads on the recurrence critical path -> 253us. Standalone at 3200 blocks: ~10us.
__global__ void k_xi2(const unsigned* __restrict__ ht0, const float* __restrict__ PT,
                      const float* __restrict__ bi2, f16* __restrict__ xi2) {
    __shared__ float hs[512];
    int tid = threadIdx.x;
    int bid = blockIdx.x;          // b*100 + t
    int b = bid / 100, t = bid % 100;
    {
        union { unsigned short s; f16 h; } c1, c2;
        c1.s = (unsigned short)ht0[(b << 9) + tid];
        c2.s = (unsigned short)ht0[(b << 9) + tid + 256];
        hs[tid] = (float)c1.h;
        hs[tid + 256] = (float)c2.h;
    }
    __syncthreads();
    int base = t * 512;
    int m0 = base / 100;
    #pragma unroll
    for (int q = 0; q < 2; ++q) {
        int o = tid + q*256;
        if (o < 450) {
            float acc = bi2[o];
            #pragma unroll
            for (int s = 0; s < 7; ++s) {
                int klo = (m0 + s)*100 - base;     klo = klo < 0 ? 0 : klo;
                int khi = (m0 + s + 1)*100 - base; khi = khi > 512 ? 512 : khi;
                if (klo < khi) {
                    float seg = PT[(size_t)khi*452 + o] - PT[(size_t)klo*452 + o];
                    acc += hs[m0 + s] * seg;
                }
            }
            xi2[(size_t)bid*512 + o] = (f16)acc;
        }
    }
}

// ---------------- GRU2: MFMA, one block per batch, B-frags register-resident ----------------
__global__ __launch_bounds__(256, 1)
void k_gru2(const f16* __restrict__ xi2, const f16* __restrict__ wh2p,
            const float* __restrict__ bh2, f16* __restrict__ decb) {
    __shared__ __align__(16) f16 hA[5*640];     // [k0][row*40+kk], row 0 real
    __shared__ float ghs[512];
    int tid = threadIdx.x;
    int b = blockIdx.x;
    int lane = tid & 63, wave = tid >> 6;
    int lrow = lane & 15, quad = lane >> 4;

    for (int i = tid; i < 5*640; i += 256) hA[i] = (f16)0.f;

    half8 Bf[8][5];
    #pragma unroll
    for (int tt = 0; tt < 8; ++tt) {
        int rn = (wave*8 + tt)*16 + lrow;
        const f16* wp = wh2p + (size_t)rn*160 + quad*8;
        #pragma unroll
        for (int k0 = 0; k0 < 5; ++k0)
            Bf[tt][k0] = *(const half8*)(wp + k0*32);
    }

    float hold = 0.f, bhr = 0.f, bhz = 0.f, bhn = 0.f;
    f16 xr = (f16)0.f, xz = (f16)0.f, xn = (f16)0.f;
    size_t xbase = (size_t)b * 100 * 512;
    if (tid < 150) {
        bhr = bh2[tid]; bhz = bh2[150 + tid]; bhn = bh2[300 + tid];
        xr = xi2[xbase + tid]; xz = xi2[xbase + 150 + tid]; xn = xi2[xbase + 300 + tid];
    }
    __syncthreads();

    for (int t = 0; t < 100; ++t) {
        float4v acc[8];
        #pragma unroll
        for (int tt = 0; tt < 8; ++tt) acc[tt] = (float4v){0.f,0.f,0.f,0.f};
        #pragma unroll
        for (int k0 = 0; k0 < 5; ++k0) {
            half8 a = *(const half8*)&hA[k0*640 + lrow*40 + quad*8];
            #pragma unroll
            for (int tt = 0; tt < 8; ++tt)
                acc[tt] = __builtin_amdgcn_mfma_f32_16x16x32_f16(a, Bf[tt][k0], acc[tt], 0, 0, 0);
        }
        if (lane < 16) {
            #pragma unroll
            for (int tt = 0; tt < 8; ++tt)
                ghs[(wave*8 + tt)*16 + lane] = acc[tt][0];
        }
        __syncthreads();

        if (tid < 150) {
            float r = fsig((float)xr + ghs[tid] + bhr);
            float z = fsig((float)xz + ghs[150 + tid] + bhz);
            float n = ftanh((float)xn + r*(ghs[300 + tid] + bhn));
            float hnew = (1.f - z)*n + z*hold;
            hold = hnew;
            f16 hh = (f16)hnew;
            hA[(tid >> 5)*640 + (tid & 31)] = hh;
            decb[((size_t)b*100 + t)*192 + tid] = hh;
            int tn = (t < 99) ? t + 1 : 99;
            size_t xo = xbase + (size_t)tn*512;
            xr = xi2[xo + tid]; xz = xi2[xo + 150 + tid]; xn = xi2[xo + 300 + tid];
        }
        __syncthreads();
    }
}

// ---------------- launch ----------------
extern "C" void kernel_launch(void* const* d_in, const int* in_sizes, int n_in,
                              void* d_out, int out_size, void* d_ws, size_t ws_size,
                              hipStream_t stream) {
    const float* window = (const float*)d_in[0];
    const float* emb    = (const float*)d_in[1];
    const float* w_init = (const float*)d_in[2];
    const float* w_root = (const float*)d_in[3];
    const float* arma_b = (const float*)d_in[4];
    const float* Wi1    = (const float*)d_in[5];
    const float* Wh1    = (const float*)d_in[6];
    const float* bi1    = (const float*)d_in[7];
    const float* bh1    = (const float*)d_in[8];
    const float* Wi2    = (const float*)d_in[9];
    const float* Wh2    = (const float*)d_in[10];
    const float* bi2    = (const float*)d_in[11];
    const float* bh2    = (const float*)d_in[12];
    const float* W_fc   = (const float*)d_in[13];
    const float* b_fc   = (const float*)d_in[14];
    float* out = (float*)d_out;

    char* ws = (char*)d_ws;
    float*    MT   = (float*)(ws + OFF_MT);
    float*    DEG  = (float*)(ws + OFF_DEG);
    unsigned* HT0  = (unsigned*)(ws + OFF_HT0);
    unsigned* HT1  = (unsigned*)(ws + OFF_HT1);
    f16*      WFCP = (f16*)  (ws + OFF_WFCP);
    f16*      WH2P = (f16*)  (ws + OFF_WH2P);
    f16*      DECB = (f16*)  (ws + OFF_DECB);
    int*      EDST = (int*)  (ws + OFF_EDST);
    float*    EVAL = (float*)(ws + OFF_EVAL);
    float*    PT   = (float*)(ws + OFF_PT);
    float*    XF   = (float*)(ws + OFF_XF);
    float*    SS   = (float*)(ws + OFF_SS);
    f16*      XT   = (f16*)  (ws + OFF_XT);
    f16*      WI1H = (f16*)  (ws + OFF_WI1H);
    f16*      XI1H = (f16*)  (ws + OFF_XI1);
    f16*      XI2H = (f16*)  (ws + OFF_XI2);

    // zero the zone (MT scatter target, deg, tagged h buffers, padded weights, dec)
    hipMemsetAsync(d_ws, 0, ZONE_END, stream);

    // graph build (norm inlined in topk)
    k_topk<<<150, 256, 0, stream>>>(emb, EDST, EVAL, DEG);

    // merged prep: finalize + weight cvts + window permute + Wi2 wave-scan prefix
    k_prep<<<31141, 256, 0, stream>>>(EDST, EVAL, DEG, MT,
                                      Wi1, WI1H, W_fc, WFCP, Wh2, WH2P,
                                      window, XF, Wi2, PT);

    // scrambled aggregation, epilogue -> xt (f16)
    k_conv<<<3200, 256, 0, stream>>>(XF, MT, SS);
    k_xt<<<3200, 256, 0, stream>>>(SS, XF, w_init, w_root, arma_b, emb, XT);

    // xi1 = xt @ Wi1^T + bi1   [3200 x 1536] f16 out, 64x128 tiles, N-major, ntm=50
    k_gemm<f16><<<50*12, 256, 0, stream>>>(XT, WI1H, bi1, XI1H, 4800, 1536, 1536, 50);

    // GRU1 scan -> h_end (tagged f16) in HT0
    k_gru1<<<256, 256, 0, stream>>>(XI1H, Wh1, bh1, HT0, HT1);

    // xi2 via repeat-interleave prefix trick (standalone, high occupancy)
    k_xi2<<<3200, 256, 0, stream>>>(HT0, PT, bi2, XI2H);

    // GRU2 scan -> dec (f16, padded K=192), MFMA version
    k_gru2<<<32, 256, 0, stream>>>(XI2H, WH2P, bh2, DECB);

    // out = dec @ W_fc^T + b_fc  -> directly into d_out [3200 x 150] (fp32)
    k_gemm<float><<<50*2, 256, 0, stream>>>(DECB, WFCP, b_fc, out, 192, 150, 150, 50);

    (void)in_sizes; (void)n_in; (void)out_size; (void)ws_size;
}